// Round 1
// 3086.943 us; speedup vs baseline: 1.7540x; 1.7540x over previous
//
#include <hip/hip_runtime.h>
#include <stdint.h>

typedef unsigned short u16;
typedef unsigned int u32;

#define NB 32      // batches per block (was 64) -> 256 blocks -> all 256 CUs
#define NWAVE 16   // waves per block
#define HISTN 64
#define TGEN 193   // L+1

// strides (elements)
#define S_NOISE 2048   // 256*8
#define S_HIST  192    // 64*3
#define S_GAP   386    // 193*2
#define S_OUT   771    // 257*3

// LDS layout (floats)
#define OFF_WHH 0                    // [j][g][k] 64*4*64 = 16384
#define OFF_WIH (OFF_WHH + 16384)    // [j][g][k16] 64*4*16 = 4096
#define OFF_W1  (OFF_WIH + 4096)     // [j][k] 64*64 = 4096
#define OFF_H   (OFF_W1 + 4096)      // [k][b] 64*32 = 2048
#define OFF_ZP  (OFF_H + 2048)       // [r][b] 32*32 = 1024
#define OFF_BIAS (OFF_ZP + 1024)     // [j*4+g] 256
#define OFF_B1  (OFF_BIAS + 256)     // 64
#define OFF_W2  (OFF_B1 + 64)        // 64
#define OFF_B2  (OFF_W2 + 64)        // 64 (pad)
#define LDS_FLOATS (OFF_B2 + 64)

__device__ __forceinline__ float b2f(u16 u) {
    return __uint_as_float(((u32)u) << 16);
}
__device__ __forceinline__ u16 f2b(float f) {
    u32 u = __float_as_uint(f);
    u32 r = (u + 0x7fffu + ((u >> 16) & 1u)) >> 16;
    return (u16)r;
}
__device__ __forceinline__ float sigf(float x) {
    return 1.0f / (1.0f + __expf(-x));
}
__device__ __forceinline__ float tanhf_(float x) {
    x = fminf(fmaxf(x, -30.0f), 30.0f);
    float e = __expf(2.0f * x);
    return (e - 1.0f) / (e + 1.0f);
}
// generic element load: idx-th element of array p under detected dtype
__device__ __forceinline__ float ldv(const void* p, int idx, bool f32) {
    return f32 ? ((const float*)p)[idx] : b2f(((const u16*)p)[idx]);
}

// One LSTM cell step. b = batch (0..31). Thread owns units j0, j0+1.
__device__ __forceinline__ void lstm_step(
    const float* whh, const float* wih, const float* bias, float* hb,
    int b, int j0, float (&c)[2], const float (&x)[12])
{
    float acc[2][4];
#pragma unroll
    for (int jj = 0; jj < 2; jj++) {
        int j = j0 + jj;
#pragma unroll
        for (int g = 0; g < 4; g++) acc[jj][g] = bias[(j << 2) | g];
    }
#pragma unroll
    for (int jj = 0; jj < 2; jj++) {
        int j = j0 + jj;
#pragma unroll
        for (int g = 0; g < 4; g++) {
            const float4* wr = reinterpret_cast<const float4*>(&wih[((j << 2) | g) << 4]);
            float a = acc[jj][g];
#pragma unroll
            for (int q = 0; q < 3; q++) {
                float4 wv = wr[q];
                a += wv.x * x[q * 4 + 0] + wv.y * x[q * 4 + 1] +
                     wv.z * x[q * 4 + 2] + wv.w * x[q * 4 + 3];
            }
            acc[jj][g] = a;
        }
    }
#pragma unroll 1
    for (int kc = 0; kc < 4; kc++) {
        float hr[16];
#pragma unroll
        for (int i = 0; i < 16; i++) hr[i] = hb[((((kc << 4) | i)) << 5) | b];
#pragma unroll
        for (int jj = 0; jj < 2; jj++) {
            int j = j0 + jj;
#pragma unroll
            for (int g = 0; g < 4; g++) {
                const float4* wr = reinterpret_cast<const float4*>(
                    &whh[(((j << 2) | g) << 6) + (kc << 4)]);
                float a = acc[jj][g];
#pragma unroll
                for (int q = 0; q < 4; q++) {
                    float4 wv = wr[q];
                    a += wv.x * hr[q * 4 + 0] + wv.y * hr[q * 4 + 1] +
                         wv.z * hr[q * 4 + 2] + wv.w * hr[q * 4 + 3];
                }
                acc[jj][g] = a;
            }
        }
    }
    float hn[2];
#pragma unroll
    for (int jj = 0; jj < 2; jj++) {
        float iv = sigf(acc[jj][0]);
        float fv = sigf(acc[jj][1]);
        float gv = tanhf_(acc[jj][2]);
        float ov = sigf(acc[jj][3]);
        float cc = fv * c[jj] + iv * gv;
        c[jj] = cc;
        hn[jj] = ov * tanhf_(cc);
    }
    __syncthreads();  // everyone done reading h_{t-1}
#pragma unroll
    for (int jj = 0; jj < 2; jj++) hb[((j0 + jj) << 5) | b] = hn[jj];
    __syncthreads();  // h_t visible
}

extern "C" __global__ void __launch_bounds__(1024)
lstm_gen_kernel(const void* __restrict__ noise, const void* __restrict__ hist_x,
                const void* __restrict__ gap, const void* __restrict__ pW_ih,
                const void* __restrict__ pW_hh, const void* __restrict__ pb_ih,
                const void* __restrict__ pb_hh, const void* __restrict__ pW1,
                const void* __restrict__ pb1, const void* __restrict__ pW2,
                const void* __restrict__ pb2, void* __restrict__ out)
{
    extern __shared__ float lds[];
    float* whh = lds + OFF_WHH;
    float* wih = lds + OFF_WIH;
    float* w1l = lds + OFF_W1;
    float* hb  = lds + OFF_H;
    float* zpl = lds + OFF_ZP;
    float* bias = lds + OFF_BIAS;
    float* b1l = lds + OFF_B1;
    float* w2l = lds + OFF_W2;
    float* b2l = lds + OFF_B2;

    const int tid = threadIdx.x;
    const int lane = tid & 63;
    const int b = lane & 31;        // batch within block
    const int half = lane >> 5;     // which half-wave unit group
    const int w = tid >> 6;         // wave 0..15
    const int j0 = (w << 2) | (half << 1);   // first of 2 owned units
    const bool writer = (tid < 32); // wave 0, half 0 -> one thread per batch
    const int batch = blockIdx.x * NB + b;

    // ---- dtype detection (wave-uniform): bf16 reading of fp32 data explodes ----
    bool is_f32 = false;
    {
        const u32* p = (const u32*)pW_hh;
        for (int i = 0; i < 64; i++) {
            u32 v = p[i];
            float a = b2f((u16)(v & 0xffffu));
            float bb = b2f((u16)(v >> 16));
            if (!(fabsf(a) <= 0.5f) || !(fabsf(bb) <= 0.5f)) is_f32 = true;  // NaN counts
        }
    }

    // ---- stage weights into LDS (fp32 compute; exact for either input dtype) ----
    for (int i = tid; i < 16384; i += 1024) {
        int j = i >> 8, g = (i >> 6) & 3, k = i & 63;
        whh[i] = ldv(pW_hh, (((g << 6) | j) << 6) | k, is_f32);
    }
    for (int i = tid; i < 4096; i += 1024) {
        int j = i >> 6, g = (i >> 4) & 3, k = i & 15;
        wih[i] = (k < 12) ? ldv(pW_ih, ((g << 6) | j) * 12 + k, is_f32) : 0.0f;
    }
    for (int i = tid; i < 4096; i += 1024) w1l[i] = ldv(pW1, i, is_f32);
    for (int i = tid; i < 2048; i += 1024) hb[i] = 0.0f;
    if (tid < 256) {
        int j = tid >> 2, g = tid & 3;
        bias[tid] = ldv(pb_ih, (g << 6) | j, is_f32) + ldv(pb_hh, (g << 6) | j, is_f32);
    }
    if (tid < 64) { b1l[tid] = ldv(pb1, tid, is_f32); w2l[tid] = ldv(pW2, tid, is_f32); }
    if (tid == 0) b2l[0] = ldv(pb2, 0, is_f32);
    __syncthreads();

    float c[2] = {0.f, 0.f};
    float dist = 0.0f;

    const u16* nzp_h = (const u16*)noise + (size_t)batch * S_NOISE;
    const float* nzp_f = (const float*)noise + (size_t)batch * S_NOISE;
    const u16* hxp_h = (const u16*)hist_x + (size_t)batch * S_HIST;
    const float* hxp_f = (const float*)hist_x + (size_t)batch * S_HIST;
    const u16* gdp_h = (const u16*)gap + (size_t)batch * S_GAP;
    const float* gdp_f = (const float*)gap + (size_t)batch * S_GAP;
    u16* outp_h = (u16*)out + (size_t)batch * S_OUT;
    float* outp_f = (float*)out + (size_t)batch * S_OUT;

    // ---- conditioning phase: 64 steps ----
#pragma unroll 1
    for (int t = 0; t < HISTN; t++) {
        float x[12];
        if (is_f32) {
            x[0] = hxp_f[t * 3 + 0]; x[1] = hxp_f[t * 3 + 1]; x[2] = hxp_f[t * 3 + 2];
            const float4* q = reinterpret_cast<const float4*>(&nzp_f[t * 8]);
            float4 a = q[0], bq = q[1];
            x[4] = a.x; x[5] = a.y; x[6] = a.z; x[7] = a.w;
            x[8] = bq.x; x[9] = bq.y; x[10] = bq.z; x[11] = bq.w;
            if (writer) {
                outp_f[t * 3 + 0] = x[0]; outp_f[t * 3 + 1] = x[1]; outp_f[t * 3 + 2] = x[2];
            }
        } else {
            u16 u0 = hxp_h[t * 3 + 0], u1 = hxp_h[t * 3 + 1], u2 = hxp_h[t * 3 + 2];
            x[0] = b2f(u0); x[1] = b2f(u1); x[2] = b2f(u2);
            const uint4 nv = *reinterpret_cast<const uint4*>(&nzp_h[t * 8]);
            x[4] = b2f((u16)(nv.x & 0xffffu)); x[5] = b2f((u16)(nv.x >> 16));
            x[6] = b2f((u16)(nv.y & 0xffffu)); x[7] = b2f((u16)(nv.y >> 16));
            x[8] = b2f((u16)(nv.z & 0xffffu)); x[9] = b2f((u16)(nv.z >> 16));
            x[10] = b2f((u16)(nv.w & 0xffffu)); x[11] = b2f((u16)(nv.w >> 16));
            if (writer) {
                outp_h[t * 3 + 0] = u0; outp_h[t * 3 + 1] = u1; outp_h[t * 3 + 2] = u2;
            }
        }
        dist += x[2];
        x[3] = dist;
        lstm_step(whh, wih, bias, hb, b, j0, c, x);
    }

    // ---- generation phase: 193 steps ----
#pragma unroll 1
    for (int tg = 0; tg < TGEN; tg++) {
        // MLP head on h_prev (in hb): z = tanh(tanh(h@W1^T + b1)@W2^T + b2)
        float macc[2];
#pragma unroll
        for (int jj = 0; jj < 2; jj++) macc[jj] = b1l[j0 + jj];
#pragma unroll 1
        for (int kc = 0; kc < 4; kc++) {
            float hr[16];
#pragma unroll
            for (int i = 0; i < 16; i++) hr[i] = hb[((((kc << 4) | i)) << 5) | b];
#pragma unroll
            for (int jj = 0; jj < 2; jj++) {
                int j = j0 + jj;
                const float4* wr = reinterpret_cast<const float4*>(&w1l[(j << 6) + (kc << 4)]);
                float a = macc[jj];
#pragma unroll
                for (int q = 0; q < 4; q++) {
                    float4 wv = wr[q];
                    a += wv.x * hr[q * 4 + 0] + wv.y * hr[q * 4 + 1] +
                         wv.z * hr[q * 4 + 2] + wv.w * hr[q * 4 + 3];
                }
                macc[jj] = a;
            }
        }
        float zpsum = w2l[j0] * tanhf_(macc[0]) + w2l[j0 + 1] * tanhf_(macc[1]);
        zpl[(((w << 1) | half) << 5) | b] = zpsum;
        __syncthreads();
        float pre2 = b2l[0];
#pragma unroll
        for (int r = 0; r < 32; r++) pre2 += zpl[(r << 5) | b];
        float z = tanhf_(pre2);
        float dp = 24.0f * z;
        dist += dp;

        float x[12];
        if (is_f32) {
            x[0] = gdp_f[tg * 2 + 0]; x[1] = gdp_f[tg * 2 + 1];
        } else {
            u32 gdu = *reinterpret_cast<const u32*>(&gdp_h[tg * 2]);
            x[0] = b2f((u16)(gdu & 0xffffu)); x[1] = b2f((u16)(gdu >> 16));
        }
        x[2] = dp; x[3] = dist;
        if (tg < TGEN - 1) {
            if (is_f32) {
                const float4* q = reinterpret_cast<const float4*>(&nzp_f[(HISTN + tg) * 8]);
                float4 a = q[0], bq = q[1];
                x[4] = a.x; x[5] = a.y; x[6] = a.z; x[7] = a.w;
                x[8] = bq.x; x[9] = bq.y; x[10] = bq.z; x[11] = bq.w;
            } else {
                const uint4 nv = *reinterpret_cast<const uint4*>(&nzp_h[(HISTN + tg) * 8]);
                x[4] = b2f((u16)(nv.x & 0xffffu)); x[5] = b2f((u16)(nv.x >> 16));
                x[6] = b2f((u16)(nv.y & 0xffffu)); x[7] = b2f((u16)(nv.y >> 16));
                x[8] = b2f((u16)(nv.z & 0xffffu)); x[9] = b2f((u16)(nv.z >> 16));
                x[10] = b2f((u16)(nv.w & 0xffffu)); x[11] = b2f((u16)(nv.w >> 16));
            }
        } else {
#pragma unroll
            for (int q = 4; q < 12; q++) x[q] = 0.0f;
        }
        if (writer) {
            if (is_f32) {
                outp_f[(HISTN + tg) * 3 + 0] = x[0];
                outp_f[(HISTN + tg) * 3 + 1] = x[1];
                outp_f[(HISTN + tg) * 3 + 2] = dp;
            } else {
                outp_h[(HISTN + tg) * 3 + 0] = f2b(x[0]);
                outp_h[(HISTN + tg) * 3 + 1] = f2b(x[1]);
                outp_h[(HISTN + tg) * 3 + 2] = f2b(dp);
            }
        }
        lstm_step(whh, wih, bias, hb, b, j0, c, x);
    }
}

extern "C" void kernel_launch(void* const* d_in, const int* in_sizes, int n_in,
                              void* d_out, int out_size, void* d_ws, size_t ws_size,
                              hipStream_t stream) {
    (void)in_sizes; (void)n_in; (void)d_ws; (void)ws_size; (void)out_size;
    const size_t smem = LDS_FLOATS * sizeof(float);  // ~110 KB
    hipFuncSetAttribute((const void*)lstm_gen_kernel,
                        hipFuncAttributeMaxDynamicSharedMemorySize, (int)smem);
    lstm_gen_kernel<<<256, 1024, smem, stream>>>(
        d_in[0], d_in[1], d_in[2], d_in[3], d_in[4], d_in[5],
        d_in[6], d_in[7], d_in[8], d_in[9], d_in[10], d_out);
}

// Round 2
// 676.123 us; speedup vs baseline: 8.0081x; 4.5657x over previous
//
#include <hip/hip_runtime.h>
#include <stdint.h>

typedef unsigned short u16;
typedef unsigned int u32;
typedef __attribute__((ext_vector_type(8))) short short8v;   // 8 bf16 = 4 VGPRs
typedef __attribute__((ext_vector_type(4))) float f32x4;

#define NB 32      // batches per block -> 256 blocks
#define HISTN 64
#define TGEN 193   // L+1

// strides (elements)
#define S_NOISE 2048   // 256*8
#define S_HIST  192    // 64*3
#define S_GAP   386    // 193*2
#define S_OUT   771    // 257*3

// h/x staging row: k=0..63 h, 64..75 x (66,67 = dp/dist slots stay ZERO; fp32 VALU path),
// 76..95 zero pad for K=96. 104 u16 = 208 B row stride (16B aligned).
#define HROW 104

__device__ __forceinline__ float b2f(u16 u) { return __uint_as_float(((u32)u) << 16); }
__device__ __forceinline__ u16 f2b(float f) {
    u32 u = __float_as_uint(f);
    u32 r = (u + 0x7fffu + ((u >> 16) & 1u)) >> 16;
    return (u16)r;
}
__device__ __forceinline__ float sigf(float x) { return 1.0f / (1.0f + __expf(-x)); }
__device__ __forceinline__ float tanhf_(float x) {
    x = fminf(fmaxf(x, -30.0f), 30.0f);
    float e = __expf(2.0f * x);
    return (e - 1.0f) / (e + 1.0f);
}
__device__ __forceinline__ float ldv(const void* p, int idx, bool f32) {
    return f32 ? ((const float*)p)[idx] : b2f(((const u16*)p)[idx]);
}
// LDS-only barrier: drain LDS ops but let owner global prefetch stay in flight
__device__ __forceinline__ void sync_lds() {
    asm volatile("s_waitcnt lgkmcnt(0)" ::: "memory");
    __builtin_amdgcn_s_barrier();
}

extern "C" __global__ void __launch_bounds__(1024)
lstm_gen_kernel(const void* __restrict__ noise, const void* __restrict__ hist_x,
                const void* __restrict__ gap, const void* __restrict__ pW_ih,
                const void* __restrict__ pW_hh, const void* __restrict__ pb_ih,
                const void* __restrict__ pb_hh, const void* __restrict__ pW1,
                const void* __restrict__ pb1, const void* __restrict__ pW2,
                const void* __restrict__ pb2, void* __restrict__ out)
{
    __shared__ u16 hst[NB * HROW];     // [b][k] bf16 staged h+x, 6656 B
    __shared__ float zpl[NB * 20];     // [b][16 pad 20] MLP partials, 2560 B
    __shared__ float dpd[NB * 2];      // [b][(val2, dist)] fp32, 256 B

    const int tid = threadIdx.x;
    const int lane = tid & 63;
    const int w = tid >> 6;        // wave 0..15 -> owns gate rows r' = 16w..16w+15 (r' = j*4+g)
    const int lg = lane >> 4;      // k-group / C-row group
    const int ln = lane & 15;      // A row within tile / batch column

    // ---- dtype detection (same proven logic) ----
    bool is_f32 = false;
    {
        const u32* p = (const u32*)pW_hh;
        for (int i = 0; i < 64; i++) {
            u32 v = p[i];
            float a = b2f((u16)(v & 0xffffu));
            float bb = b2f((u16)(v >> 16));
            if (!(fabsf(a) <= 0.5f) || !(fabsf(bb) <= 0.5f)) is_f32 = true;
        }
    }

    for (int i = tid; i < NB * HROW / 2; i += 1024) ((u32*)hst)[i] = 0u;

    // ---- persistent A fragments (LSTM weights), unit-major rows r' = j*4+g ----
    // A-side: lane row m = ln -> r' = 16w+ln -> j = 4w+(ln>>2), gate = ln&3
    short8v aF0, aF1, aF2;
    {
        const int ja = (w << 2) | (ln >> 2);
        const int ga = ln & 3;
        const int row = (ga << 6) | ja;   // original weight row = gate*64 + j
#pragma unroll
        for (int e = 0; e < 8; e++) {
            int k0 = lg * 8 + e;
            aF0[e] = (short)f2b(ldv(pW_hh, row * 64 + k0, is_f32));
            aF1[e] = (short)f2b(ldv(pW_hh, row * 64 + 32 + k0, is_f32));
            float v = 0.0f;
            int cI = 64 + k0 - 64;  // = k0
            if (k0 < 12 && k0 != 2 && k0 != 3) v = ldv(pW_ih, row * 12 + k0, is_f32);
            (void)cI;
            aF2[e] = (short)f2b(v);
        }
    }

    // C-side per-lane rows r' = 16w + lg*4 + q -> j = 4w+lg, gate = q
    float biasL[4], wdpL[4], wdistL[4];
    {
        const int jc = (w << 2) | lg;
#pragma unroll
        for (int q = 0; q < 4; q++) {
            int row = (q << 6) | jc;
            biasL[q]  = ldv(pb_ih, row, is_f32) + ldv(pb_hh, row, is_f32);
            wdpL[q]   = ldv(pW_ih, row * 12 + 2, is_f32);   // dp column (fp32 path)
            wdistL[q] = ldv(pW_ih, row * 12 + 3, is_f32);   // dist column (fp32 path)
        }
    }

    // ---- MLP head fragments (waves 4..7 own W1 rows 16(w-4)..+16) ----
    const bool mlpw = (w >= 4) && (w < 8);
    short8v w1F0 = {}, w1F1 = {};
    float b1L[4] = {0.f, 0.f, 0.f, 0.f}, w2L[4] = {0.f, 0.f, 0.f, 0.f};
    if (mlpw) {
        const int wp = w - 4;
        const int row1 = (wp << 4) | ln;
#pragma unroll
        for (int e = 0; e < 8; e++) {
            w1F0[e] = (short)f2b(ldv(pW1, row1 * 64 + lg * 8 + e, is_f32));
            w1F1[e] = (short)f2b(ldv(pW1, row1 * 64 + 32 + lg * 8 + e, is_f32));
        }
        const int rq = (wp << 4) | (lg << 2);
#pragma unroll
        for (int q = 0; q < 4; q++) {
            b1L[q] = ldv(pb1, rq + q, is_f32);
            w2L[q] = ldv(pW2, rq + q, is_f32);
        }
    }

    // ---- owner lanes: per-batch scalar state + input prefetch ----
    const bool owner = tid < NB;
    const size_t gb = (size_t)blockIdx.x * NB + (size_t)(tid & (NB - 1));
    const u16* nz_h = (const u16*)noise + gb * S_NOISE;
    const float* nz_f = (const float*)noise + gb * S_NOISE;
    const u16* hx_h = (const u16*)hist_x + gb * S_HIST;
    const float* hx_f = (const float*)hist_x + gb * S_HIST;
    const u16* gd_h = (const u16*)gap + gb * S_GAP;
    const float* gd_f = (const float*)gap + gb * S_GAP;
    u16* out_h = (u16*)out + gb * S_OUT;
    float* out_f = (float*)out + gb * S_OUT;

    float dist = 0.0f, b2v = 0.0f;
    float cv0 = 0.f, cv1 = 0.f, cv2 = 0.f;
    u32 n01 = 0, n23 = 0, n45 = 0, n67 = 0;

    auto ldnoise = [&](int t) {
        if (is_f32) {
            const float4* q = (const float4*)(nz_f + t * 8);
            float4 a = q[0], bq = q[1];
            n01 = (u32)f2b(a.x) | ((u32)f2b(a.y) << 16);
            n23 = (u32)f2b(a.z) | ((u32)f2b(a.w) << 16);
            n45 = (u32)f2b(bq.x) | ((u32)f2b(bq.y) << 16);
            n67 = (u32)f2b(bq.z) | ((u32)f2b(bq.w) << 16);
        } else {
            uint4 nv = *(const uint4*)(nz_h + t * 8);
            n01 = nv.x; n23 = nv.y; n45 = nv.z; n67 = nv.w;
        }
    };

    if (owner) {
        b2v = ldv(pb2, 0, is_f32);
        if (is_f32) { cv0 = hx_f[0]; cv1 = hx_f[1]; cv2 = hx_f[2]; }
        else { cv0 = b2f(hx_h[0]); cv1 = b2f(hx_h[1]); cv2 = b2f(hx_h[2]); }
        ldnoise(0);
    }

    float cst0 = 0.f, cst1 = 0.f;
    __syncthreads();

    // ================= conditioning: 64 steps =================
#pragma unroll 1
    for (int t = 0; t < HISTN; t++) {
        short8v bf00 = *(const short8v*)&hst[ln * HROW + lg * 8];
        short8v bf01 = *(const short8v*)&hst[ln * HROW + 32 + lg * 8];
        short8v bf10 = *(const short8v*)&hst[(16 + ln) * HROW + lg * 8];
        short8v bf11 = *(const short8v*)&hst[(16 + ln) * HROW + 32 + lg * 8];
        if (owner) {
            const int ob = tid;
            dist += cv2;
            dpd[ob * 2] = cv2; dpd[ob * 2 + 1] = dist;
            u16* hr = &hst[ob * HROW];
            *(u32*)&hr[64] = (u32)f2b(cv0) | ((u32)f2b(cv1) << 16);
            *(u32*)&hr[68] = n01; *(u32*)&hr[70] = n23;
            *(u32*)&hr[72] = n45; *(u32*)&hr[74] = n67;
        }
        sync_lds();
        if (owner) {   // out-write + prefetch overlap the mfma phase below
            if (is_f32) { out_f[t*3] = cv0; out_f[t*3+1] = cv1; out_f[t*3+2] = cv2; }
            else { out_h[t*3] = f2b(cv0); out_h[t*3+1] = f2b(cv1); out_h[t*3+2] = f2b(cv2); }
            if (t + 1 < HISTN) {
                if (is_f32) { cv0 = hx_f[(t+1)*3]; cv1 = hx_f[(t+1)*3+1]; cv2 = hx_f[(t+1)*3+2]; }
                else { cv0 = b2f(hx_h[(t+1)*3]); cv1 = b2f(hx_h[(t+1)*3+1]); cv2 = b2f(hx_h[(t+1)*3+2]); }
                ldnoise(t + 1);
            } else {
                if (is_f32) { cv0 = gd_f[0]; cv1 = gd_f[1]; }
                else { u32 g = *(const u32*)gd_h; cv0 = b2f((u16)(g & 0xffffu)); cv1 = b2f((u16)(g >> 16)); }
                ldnoise(HISTN);
            }
        }
        short8v bf02 = *(const short8v*)&hst[ln * HROW + 64 + lg * 8];
        short8v bf12 = *(const short8v*)&hst[(16 + ln) * HROW + 64 + lg * 8];
        float2 d0 = *(const float2*)&dpd[ln * 2];
        float2 d1 = *(const float2*)&dpd[(16 + ln) * 2];
        f32x4 acc0, acc1;
#pragma unroll
        for (int q = 0; q < 4; q++) {
            acc0[q] = biasL[q] + wdpL[q] * d0.x + wdistL[q] * d0.y;
            acc1[q] = biasL[q] + wdpL[q] * d1.x + wdistL[q] * d1.y;
        }
        acc0 = __builtin_amdgcn_mfma_f32_16x16x32_bf16(aF0, bf00, acc0, 0, 0, 0);
        acc0 = __builtin_amdgcn_mfma_f32_16x16x32_bf16(aF1, bf01, acc0, 0, 0, 0);
        acc0 = __builtin_amdgcn_mfma_f32_16x16x32_bf16(aF2, bf02, acc0, 0, 0, 0);
        acc1 = __builtin_amdgcn_mfma_f32_16x16x32_bf16(aF0, bf10, acc1, 0, 0, 0);
        acc1 = __builtin_amdgcn_mfma_f32_16x16x32_bf16(aF1, bf11, acc1, 0, 0, 0);
        acc1 = __builtin_amdgcn_mfma_f32_16x16x32_bf16(aF2, bf12, acc1, 0, 0, 0);
        float h0, h1;
        { float iv = sigf(acc0[0]), fv = sigf(acc0[1]), gv = tanhf_(acc0[2]), ov = sigf(acc0[3]);
          cst0 = fv * cst0 + iv * gv; h0 = ov * tanhf_(cst0); }
        { float iv = sigf(acc1[0]), fv = sigf(acc1[1]), gv = tanhf_(acc1[2]), ov = sigf(acc1[3]);
          cst1 = fv * cst1 + iv * gv; h1 = ov * tanhf_(cst1); }
        const int ju = (w << 2) | lg;
        hst[ln * HROW + ju] = f2b(h0);
        hst[(16 + ln) * HROW + ju] = f2b(h1);
        sync_lds();
    }

    // ================= generation: 193 steps =================
#pragma unroll 1
    for (int tg = 0; tg < TGEN; tg++) {
        short8v bf00 = *(const short8v*)&hst[ln * HROW + lg * 8];
        short8v bf01 = *(const short8v*)&hst[ln * HROW + 32 + lg * 8];
        short8v bf10 = *(const short8v*)&hst[(16 + ln) * HROW + lg * 8];
        short8v bf11 = *(const short8v*)&hst[(16 + ln) * HROW + 32 + lg * 8];
        if (mlpw) {   // MLP head reuses the same h B-fragments
            f32x4 m0 = {b1L[0], b1L[1], b1L[2], b1L[3]};
            f32x4 m1 = m0;
            m0 = __builtin_amdgcn_mfma_f32_16x16x32_bf16(w1F0, bf00, m0, 0, 0, 0);
            m0 = __builtin_amdgcn_mfma_f32_16x16x32_bf16(w1F1, bf01, m0, 0, 0, 0);
            m1 = __builtin_amdgcn_mfma_f32_16x16x32_bf16(w1F0, bf10, m1, 0, 0, 0);
            m1 = __builtin_amdgcn_mfma_f32_16x16x32_bf16(w1F1, bf11, m1, 0, 0, 0);
            float p0 = 0.f, p1 = 0.f;
#pragma unroll
            for (int q = 0; q < 4; q++) {
                p0 += w2L[q] * tanhf_(m0[q]);
                p1 += w2L[q] * tanhf_(m1[q]);
            }
            const int p = ((w - 4) << 2) | lg;
            zpl[ln * 20 + p] = p0;
            zpl[(16 + ln) * 20 + p] = p1;
        }
        sync_lds();   // barrier 1: partials visible
        if (owner) {
            const int ob = tid;
            const float4* zr = (const float4*)&zpl[ob * 20];
            float4 z0 = zr[0], z1 = zr[1], z2 = zr[2], z3 = zr[3];
            float pre2 = b2v + z0.x + z0.y + z0.z + z0.w + z1.x + z1.y + z1.z + z1.w
                       + z2.x + z2.y + z2.z + z2.w + z3.x + z3.y + z3.z + z3.w;
            float zz = tanhf_(pre2);
            float dp = 24.0f * zz;
            dist += dp;
            dpd[ob * 2] = dp; dpd[ob * 2 + 1] = dist;
            u16* hr = &hst[ob * HROW];
            *(u32*)&hr[64] = (u32)f2b(cv0) | ((u32)f2b(cv1) << 16);
            *(u32*)&hr[68] = n01; *(u32*)&hr[70] = n23;
            *(u32*)&hr[72] = n45; *(u32*)&hr[74] = n67;
            const int to = HISTN + tg;
            if (is_f32) { out_f[to*3] = cv0; out_f[to*3+1] = cv1; out_f[to*3+2] = dp; }
            else { out_h[to*3] = f2b(cv0); out_h[to*3+1] = f2b(cv1); out_h[to*3+2] = f2b(dp); }
        }
        sync_lds();   // barrier 2: x + dpd visible
        if (owner && tg + 1 < TGEN) {   // prefetch rides over LDS-only barriers
            if (is_f32) { cv0 = gd_f[(tg+1)*2]; cv1 = gd_f[(tg+1)*2+1]; }
            else { u32 g = *(const u32*)(gd_h + (tg+1)*2);
                   cv0 = b2f((u16)(g & 0xffffu)); cv1 = b2f((u16)(g >> 16)); }
            if (tg + 1 < TGEN - 1) ldnoise(HISTN + tg + 1);
            else { n01 = n23 = n45 = n67 = 0; }
        }
        short8v bf02 = *(const short8v*)&hst[ln * HROW + 64 + lg * 8];
        short8v bf12 = *(const short8v*)&hst[(16 + ln) * HROW + 64 + lg * 8];
        float2 d0 = *(const float2*)&dpd[ln * 2];
        float2 d1 = *(const float2*)&dpd[(16 + ln) * 2];
        f32x4 acc0, acc1;
#pragma unroll
        for (int q = 0; q < 4; q++) {
            acc0[q] = biasL[q] + wdpL[q] * d0.x + wdistL[q] * d0.y;
            acc1[q] = biasL[q] + wdpL[q] * d1.x + wdistL[q] * d1.y;
        }
        acc0 = __builtin_amdgcn_mfma_f32_16x16x32_bf16(aF0, bf00, acc0, 0, 0, 0);
        acc0 = __builtin_amdgcn_mfma_f32_16x16x32_bf16(aF1, bf01, acc0, 0, 0, 0);
        acc0 = __builtin_amdgcn_mfma_f32_16x16x32_bf16(aF2, bf02, acc0, 0, 0, 0);
        acc1 = __builtin_amdgcn_mfma_f32_16x16x32_bf16(aF0, bf10, acc1, 0, 0, 0);
        acc1 = __builtin_amdgcn_mfma_f32_16x16x32_bf16(aF1, bf11, acc1, 0, 0, 0);
        acc1 = __builtin_amdgcn_mfma_f32_16x16x32_bf16(aF2, bf12, acc1, 0, 0, 0);
        float h0, h1;
        { float iv = sigf(acc0[0]), fv = sigf(acc0[1]), gv = tanhf_(acc0[2]), ov = sigf(acc0[3]);
          cst0 = fv * cst0 + iv * gv; h0 = ov * tanhf_(cst0); }
        { float iv = sigf(acc1[0]), fv = sigf(acc1[1]), gv = tanhf_(acc1[2]), ov = sigf(acc1[3]);
          cst1 = fv * cst1 + iv * gv; h1 = ov * tanhf_(cst1); }
        const int ju = (w << 2) | lg;
        hst[ln * HROW + ju] = f2b(h0);
        hst[(16 + ln) * HROW + ju] = f2b(h1);
        sync_lds();   // barrier 3: h visible
    }
}

extern "C" void kernel_launch(void* const* d_in, const int* in_sizes, int n_in,
                              void* d_out, int out_size, void* d_ws, size_t ws_size,
                              hipStream_t stream) {
    (void)in_sizes; (void)n_in; (void)d_ws; (void)ws_size; (void)out_size;
    lstm_gen_kernel<<<256, 1024, 0, stream>>>(
        d_in[0], d_in[1], d_in[2], d_in[3], d_in[4], d_in[5],
        d_in[6], d_in[7], d_in[8], d_in[9], d_in[10], d_out);
}

// Round 3
// 500.562 us; speedup vs baseline: 10.8167x; 1.3507x over previous
//
#include <hip/hip_runtime.h>
#include <stdint.h>

typedef unsigned short u16;
typedef unsigned int u32;
typedef __attribute__((ext_vector_type(8))) short short8v;   // 8 bf16 = 4 VGPRs
typedef __attribute__((ext_vector_type(4))) float f32x4;

#define NB 16      // batches per block -> 512 blocks -> 2 blocks/CU
#define HISTN 64
#define TGEN 193   // L+1

// strides (elements)
#define S_NOISE 2048   // 256*8
#define S_HIST  192    // 64*3
#define S_GAP   386    // 193*2
#define S_OUT   771    // 257*3

// hst row: k0..63 h | k64 x0, k65 x1, k66 dp_hi, k67 dp_lo, k68 dist_hi,
// k69 dist_lo, k70 dist_hi(dup, pairs wdist_lo), k71 dp_hi(dup, pairs wdp_lo),
// k72..79 noise, k80..95 zero, k96..103 pad. 104 u16 = 208 B = 13x16B (odd
// chunk stride -> owner u32 writes 2-way/free, b128 reads uniform 8/bank).
#define HROW 104

__device__ __forceinline__ float b2f(u16 u) { return __uint_as_float(((u32)u) << 16); }
__device__ __forceinline__ u16 f2b(float f) {
    u32 u = __float_as_uint(f);
    u32 r = (u + 0x7fffu + ((u >> 16) & 1u)) >> 16;
    return (u16)r;
}
// fast transcendentals: v_rcp_f32 (~1 ulp) instead of full-precision v_div
__device__ __forceinline__ float rcp_(float x) { return __builtin_amdgcn_rcpf(x); }
__device__ __forceinline__ float sigf(float x) { return rcp_(1.0f + __expf(-x)); }
__device__ __forceinline__ float tanhf_(float x) {
    // 1 - 2/(1+e^{2x}); exp saturation gives exact +/-1 at large |x|, no clamp
    return __builtin_fmaf(-2.0f, rcp_(1.0f + __expf(2.0f * x)), 1.0f);
}
__device__ __forceinline__ float ldv(const void* p, int idx, bool f32) {
    return f32 ? ((const float*)p)[idx] : b2f(((const u16*)p)[idx]);
}
// LDS-only barrier: drain LDS ops but let owner global prefetch stay in flight
__device__ __forceinline__ void sync_lds() {
    asm volatile("s_waitcnt lgkmcnt(0)" ::: "memory");
    __builtin_amdgcn_s_barrier();
}

extern "C" __global__ void __launch_bounds__(512, 4)
lstm_gen_kernel(const void* __restrict__ noise, const void* __restrict__ hist_x,
                const void* __restrict__ gap, const void* __restrict__ pW_ih,
                const void* __restrict__ pW_hh, const void* __restrict__ pb_ih,
                const void* __restrict__ pb_hh, const void* __restrict__ pW1,
                const void* __restrict__ pb1, const void* __restrict__ pW2,
                const void* __restrict__ pb2, void* __restrict__ out)
{
    __shared__ u16 hst[NB * HROW];     // 3328 B
    __shared__ float zpl[NB * 20];     // 1280 B

    const int tid = threadIdx.x;
    const int lane = tid & 63;
    const int w = tid >> 6;        // wave 0..7
    const int lg = lane >> 4;      // k-group / C-row group
    const int ln = lane & 15;      // A/C row-col index = batch column

    // ---- dtype detection (proven logic) ----
    bool is_f32 = false;
    {
        const u32* p = (const u32*)pW_hh;
        for (int i = 0; i < 64; i++) {
            u32 v = p[i];
            float a = b2f((u16)(v & 0xffffu));
            float bb = b2f((u16)(v >> 16));
            if (!(fabsf(a) <= 0.5f) || !(fabsf(bb) <= 0.5f)) is_f32 = true;
        }
    }

    for (int i = tid; i < NB * HROW / 2; i += 512) ((u32*)hst)[i] = 0u;

    // ---- persistent A fragments: wave w owns gate-row tiles [16w,16w+16) and
    // [128+16w, ...): units 4w+lg and 32+4w+lg per lane on the C side ----
    short8v a00, a01, a02, a10, a11, a12;
#pragma unroll
    for (int T = 0; T < 2; T++) {
        const int j = (T << 5) | (w << 2) | (ln >> 2);
        const int g = ln & 3;
        const int row = (g << 6) | j;   // original weight row = gate*64 + unit
        float wdp = ldv(pW_ih, row * 12 + 2, is_f32);
        u16 wdph = f2b(wdp);
        u16 wdpl = f2b(wdp - b2f(wdph));
        float wds = ldv(pW_ih, row * 12 + 3, is_f32);
        u16 wdsh = f2b(wds);
        u16 wdsl = f2b(wds - b2f(wdsh));
        short8v f0, f1, f2;
#pragma unroll
        for (int e = 0; e < 8; e++) {
            const int c = lg * 8 + e;
            f0[e] = (short)f2b(ldv(pW_hh, row * 64 + c, is_f32));
            f1[e] = (short)f2b(ldv(pW_hh, row * 64 + 32 + c, is_f32));
            u16 v = 0;
            if (c == 0 || c == 1) v = f2b(ldv(pW_ih, row * 12 + c, is_f32));
            else if (c == 2 || c == 3) v = wdph;       // x dp_hi, dp_lo
            else if (c == 4 || c == 5) v = wdsh;       // x dist_hi, dist_lo
            else if (c == 6) v = wdsl;                 // x dist_hi (dup)
            else if (c == 7) v = wdpl;                 // x dp_hi (dup)
            else if (c >= 8 && c < 16) v = f2b(ldv(pW_ih, row * 12 + (c - 4), is_f32));
            f2[e] = (short)v;
        }
        if (T == 0) { a00 = f0; a01 = f1; a02 = f2; }
        else        { a10 = f0; a11 = f1; a12 = f2; }
    }

    // C-side biases: rows r' = tile*128 + 16w + lg*4 + q
    f32x4 bias0, bias1;
#pragma unroll
    for (int T = 0; T < 2; T++) {
        const int jc = (T << 5) | (w << 2) | lg;
        f32x4 bv;
#pragma unroll
        for (int q = 0; q < 4; q++) {
            const int row = (q << 6) | jc;
            bv[q] = ldv(pb_ih, row, is_f32) + ldv(pb_hh, row, is_f32);
        }
        if (T == 0) bias0 = bv; else bias1 = bv;
    }

    // ---- MLP head fragments (waves 4..7 own W1 rows 16(w-4)..+16) ----
    const bool mlpw = (w >= 4);
    short8v w1F0 = {}, w1F1 = {};
    f32x4 b1v = {0.f, 0.f, 0.f, 0.f};
    float w2L[4] = {0.f, 0.f, 0.f, 0.f};
    if (mlpw) {
        const int wp = w - 4;
        const int row1 = (wp << 4) | ln;
#pragma unroll
        for (int e = 0; e < 8; e++) {
            w1F0[e] = (short)f2b(ldv(pW1, row1 * 64 + lg * 8 + e, is_f32));
            w1F1[e] = (short)f2b(ldv(pW1, row1 * 64 + 32 + lg * 8 + e, is_f32));
        }
        const int rq = (wp << 4) | (lg << 2);
#pragma unroll
        for (int q = 0; q < 4; q++) {
            b1v[q] = ldv(pb1, rq + q, is_f32);
            w2L[q] = ldv(pW2, rq + q, is_f32);
        }
    }

    // ---- owner lanes (tid<16, wave 0): per-batch scalar state + prefetch ----
    const bool owner = tid < NB;
    const size_t gb = (size_t)blockIdx.x * NB + (size_t)(tid & (NB - 1));
    const u16* nz_h = (const u16*)noise + gb * S_NOISE;
    const float* nz_f = (const float*)noise + gb * S_NOISE;
    const u16* hx_h = (const u16*)hist_x + gb * S_HIST;
    const float* hx_f = (const float*)hist_x + gb * S_HIST;
    const u16* gd_h = (const u16*)gap + gb * S_GAP;
    const float* gd_f = (const float*)gap + gb * S_GAP;
    u16* out_h = (u16*)out + gb * S_OUT;
    float* out_f = (float*)out + gb * S_OUT;

    float dist = 0.0f, b2v = 0.0f;
    float cv0 = 0.f, cv1 = 0.f, cv2 = 0.f;
    u32 n01 = 0, n23 = 0, n45 = 0, n67 = 0;

    auto ldnoise = [&](int t) {
        if (is_f32) {
            const float4* q = (const float4*)(nz_f + t * 8);
            float4 a = q[0], bq = q[1];
            n01 = (u32)f2b(a.x) | ((u32)f2b(a.y) << 16);
            n23 = (u32)f2b(a.z) | ((u32)f2b(a.w) << 16);
            n45 = (u32)f2b(bq.x) | ((u32)f2b(bq.y) << 16);
            n67 = (u32)f2b(bq.z) | ((u32)f2b(bq.w) << 16);
        } else {
            uint4 nv = *(const uint4*)(nz_h + t * 8);
            n01 = nv.x; n23 = nv.y; n45 = nv.z; n67 = nv.w;
        }
    };

    if (owner) {
        b2v = ldv(pb2, 0, is_f32);
        if (is_f32) { cv0 = hx_f[0]; cv1 = hx_f[1]; cv2 = hx_f[2]; }
        else { cv0 = b2f(hx_h[0]); cv1 = b2f(hx_h[1]); cv2 = b2f(hx_h[2]); }
        ldnoise(0);
    }

    float cst0 = 0.f, cst1 = 0.f;
    __syncthreads();

    // ================= conditioning: 64 steps =================
#pragma unroll 1
    for (int t = 0; t < HISTN; t++) {
        short8v bf0 = *(const short8v*)&hst[ln * HROW + lg * 8];
        short8v bf1 = *(const short8v*)&hst[ln * HROW + 32 + lg * 8];
        if (owner) {
            dist += cv2;
            u16 dph = f2b(cv2); u16 dpl = f2b(cv2 - b2f(dph));
            u16 dsh = f2b(dist); u16 dsl = f2b(dist - b2f(dsh));
            u16* hr = &hst[tid * HROW];
            *(u32*)&hr[64] = (u32)f2b(cv0) | ((u32)f2b(cv1) << 16);
            *(u32*)&hr[66] = (u32)dph | ((u32)dpl << 16);
            *(u32*)&hr[68] = (u32)dsh | ((u32)dsl << 16);
            *(u32*)&hr[70] = (u32)dsh | ((u32)dph << 16);
            *(u32*)&hr[72] = n01; *(u32*)&hr[74] = n23;
            *(u32*)&hr[76] = n45; *(u32*)&hr[78] = n67;
        }
        sync_lds();   // x visible
        if (owner) {  // out-write + prefetch overlap mfma below
            if (is_f32) { out_f[t*3] = cv0; out_f[t*3+1] = cv1; out_f[t*3+2] = cv2; }
            else { out_h[t*3] = f2b(cv0); out_h[t*3+1] = f2b(cv1); out_h[t*3+2] = f2b(cv2); }
            if (t + 1 < HISTN) {
                if (is_f32) { cv0 = hx_f[(t+1)*3]; cv1 = hx_f[(t+1)*3+1]; cv2 = hx_f[(t+1)*3+2]; }
                else { cv0 = b2f(hx_h[(t+1)*3]); cv1 = b2f(hx_h[(t+1)*3+1]); cv2 = b2f(hx_h[(t+1)*3+2]); }
                ldnoise(t + 1);
            } else {
                if (is_f32) { cv0 = gd_f[0]; cv1 = gd_f[1]; }
                else { u32 g = *(const u32*)gd_h; cv0 = b2f((u16)(g & 0xffffu)); cv1 = b2f((u16)(g >> 16)); }
                ldnoise(HISTN);
            }
        }
        short8v bf2 = *(const short8v*)&hst[ln * HROW + 64 + lg * 8];
        f32x4 acc0 = bias0, acc1 = bias1;
        acc0 = __builtin_amdgcn_mfma_f32_16x16x32_bf16(a00, bf0, acc0, 0, 0, 0);
        acc0 = __builtin_amdgcn_mfma_f32_16x16x32_bf16(a01, bf1, acc0, 0, 0, 0);
        acc0 = __builtin_amdgcn_mfma_f32_16x16x32_bf16(a02, bf2, acc0, 0, 0, 0);
        acc1 = __builtin_amdgcn_mfma_f32_16x16x32_bf16(a10, bf0, acc1, 0, 0, 0);
        acc1 = __builtin_amdgcn_mfma_f32_16x16x32_bf16(a11, bf1, acc1, 0, 0, 0);
        acc1 = __builtin_amdgcn_mfma_f32_16x16x32_bf16(a12, bf2, acc1, 0, 0, 0);
        float h0, h1;
        { float iv = sigf(acc0[0]), fv = sigf(acc0[1]), gv = tanhf_(acc0[2]), ov = sigf(acc0[3]);
          cst0 = fv * cst0 + iv * gv; h0 = ov * tanhf_(cst0); }
        { float iv = sigf(acc1[0]), fv = sigf(acc1[1]), gv = tanhf_(acc1[2]), ov = sigf(acc1[3]);
          cst1 = fv * cst1 + iv * gv; h1 = ov * tanhf_(cst1); }
        const int j0 = (w << 2) | lg;
        hst[ln * HROW + j0] = f2b(h0);
        hst[ln * HROW + j0 + 32] = f2b(h1);
        sync_lds();   // h visible
    }

    // ================= generation: 193 steps =================
#pragma unroll 1
    for (int tg = 0; tg < TGEN; tg++) {
        short8v bf0 = *(const short8v*)&hst[ln * HROW + lg * 8];
        short8v bf1 = *(const short8v*)&hst[ln * HROW + 32 + lg * 8];
        if (mlpw) {   // MLP head reuses the same h B-fragments
            f32x4 m0 = b1v;
            m0 = __builtin_amdgcn_mfma_f32_16x16x32_bf16(w1F0, bf0, m0, 0, 0, 0);
            m0 = __builtin_amdgcn_mfma_f32_16x16x32_bf16(w1F1, bf1, m0, 0, 0, 0);
            float p0 = w2L[0] * tanhf_(m0[0]) + w2L[1] * tanhf_(m0[1])
                     + w2L[2] * tanhf_(m0[2]) + w2L[3] * tanhf_(m0[3]);
            zpl[ln * 20 + (((w - 4) << 2) | lg)] = p0;
        }
        sync_lds();   // B1: partials visible
        if (owner) {
            const float4* zr = (const float4*)&zpl[tid * 20];
            float4 z0 = zr[0], z1 = zr[1], z2 = zr[2], z3 = zr[3];
            float pre2 = b2v + z0.x + z0.y + z0.z + z0.w + z1.x + z1.y + z1.z + z1.w
                       + z2.x + z2.y + z2.z + z2.w + z3.x + z3.y + z3.z + z3.w;
            float zz = tanhf_(pre2);
            float dp = 24.0f * zz;
            dist += dp;
            u16 dph = f2b(dp); u16 dpl = f2b(dp - b2f(dph));
            u16 dsh = f2b(dist); u16 dsl = f2b(dist - b2f(dsh));
            u16* hr = &hst[tid * HROW];
            *(u32*)&hr[64] = (u32)f2b(cv0) | ((u32)f2b(cv1) << 16);
            *(u32*)&hr[66] = (u32)dph | ((u32)dpl << 16);
            *(u32*)&hr[68] = (u32)dsh | ((u32)dsl << 16);
            *(u32*)&hr[70] = (u32)dsh | ((u32)dph << 16);
            *(u32*)&hr[72] = n01; *(u32*)&hr[74] = n23;
            *(u32*)&hr[76] = n45; *(u32*)&hr[78] = n67;
            const int to = HISTN + tg;
            if (is_f32) { out_f[to*3] = cv0; out_f[to*3+1] = cv1; out_f[to*3+2] = dp; }
            else { out_h[to*3] = f2b(cv0); out_h[to*3+1] = f2b(cv1); out_h[to*3+2] = f2b(dp); }
        }
        sync_lds();   // B2: x visible
        if (owner && tg + 1 < TGEN) {   // prefetch rides over LDS-only barriers
            if (is_f32) { cv0 = gd_f[(tg+1)*2]; cv1 = gd_f[(tg+1)*2+1]; }
            else { u32 g = *(const u32*)(gd_h + (tg+1)*2);
                   cv0 = b2f((u16)(g & 0xffffu)); cv1 = b2f((u16)(g >> 16)); }
            if (tg + 1 < TGEN - 1) ldnoise(HISTN + tg + 1);
            else { n01 = n23 = n45 = n67 = 0; }
        }
        short8v bf2 = *(const short8v*)&hst[ln * HROW + 64 + lg * 8];
        f32x4 acc0 = bias0, acc1 = bias1;
        acc0 = __builtin_amdgcn_mfma_f32_16x16x32_bf16(a00, bf0, acc0, 0, 0, 0);
        acc0 = __builtin_amdgcn_mfma_f32_16x16x32_bf16(a01, bf1, acc0, 0, 0, 0);
        acc0 = __builtin_amdgcn_mfma_f32_16x16x32_bf16(a02, bf2, acc0, 0, 0, 0);
        acc1 = __builtin_amdgcn_mfma_f32_16x16x32_bf16(a10, bf0, acc1, 0, 0, 0);
        acc1 = __builtin_amdgcn_mfma_f32_16x16x32_bf16(a11, bf1, acc1, 0, 0, 0);
        acc1 = __builtin_amdgcn_mfma_f32_16x16x32_bf16(a12, bf2, acc1, 0, 0, 0);
        float h0, h1;
        { float iv = sigf(acc0[0]), fv = sigf(acc0[1]), gv = tanhf_(acc0[2]), ov = sigf(acc0[3]);
          cst0 = fv * cst0 + iv * gv; h0 = ov * tanhf_(cst0); }
        { float iv = sigf(acc1[0]), fv = sigf(acc1[1]), gv = tanhf_(acc1[2]), ov = sigf(acc1[3]);
          cst1 = fv * cst1 + iv * gv; h1 = ov * tanhf_(cst1); }
        const int j0 = (w << 2) | lg;
        hst[ln * HROW + j0] = f2b(h0);
        hst[ln * HROW + j0 + 32] = f2b(h1);
        sync_lds();   // B3: h visible
    }
}

extern "C" void kernel_launch(void* const* d_in, const int* in_sizes, int n_in,
                              void* d_out, int out_size, void* d_ws, size_t ws_size,
                              hipStream_t stream) {
    (void)in_sizes; (void)n_in; (void)d_ws; (void)ws_size; (void)out_size;
    lstm_gen_kernel<<<512, 512, 0, stream>>>(
        d_in[0], d_in[1], d_in[2], d_in[3], d_in[4], d_in[5],
        d_in[6], d_in[7], d_in[8], d_in[9], d_in[10], d_out);
}